// Round 1
// baseline (152.738 us; speedup 1.0000x reference)
//
#include <hip/hip_runtime.h>
#include <math.h>

#define NT 365
#define NS 128
#define NG 16
#define NH 8
#define HS 256
#define EPSC 1e-6f

// Workspace layout (floats):
//   state: NS*HS            @ 0        (32768)
//   prm:   6*NS*NH          @ 32768    (6144)   order: gk, gl, qb, ga, gi, ge
//   km:    NT*NS*NH         @ 38912    (373760)
//   ps:    NT*NS            @ 412672   (46720)
//   pl:    NT*NS            @ 459392   (46720)
// total 506112 floats = 2,024,448 bytes
#define WS_STATE 0
#define WS_PRM   32768
#define WS_KM    38912
#define WS_PS    412672
#define WS_PL    459392

// ---------------- K0: per-site state + parameter heads -----------------
__global__ __launch_bounds__(256) void k_params(
    const float* __restrict__ xc, const float* __restrict__ W_fc,
    const float* __restrict__ b_fc, const float* __restrict__ W_g,
    const float* __restrict__ b_g, float* __restrict__ state,
    float* __restrict__ prm)
{
    int s = blockIdx.x;
    int j = threadIdx.x;
    __shared__ float ts[HS];
    __shared__ float pgs[6 * NH];

    // state[s, j] = b_fc[j] + sum_g xc[s,g] * W_fc[j,g]
    float acc = b_fc[j];
    const float* xrow = xc + s * NG;
#pragma unroll
    for (int g = 0; g < NG; ++g) acc += xrow[g] * W_fc[j * NG + g];
    state[s * HS + j] = acc;
    ts[j] = tanhf(acc);
    __syncthreads();

    // pg[k] = b_g[k] + sum_j ts[j] * W_g[k, j]   for k = 0..47
    int wave = j >> 6, lane = j & 63;
    for (int k = wave; k < 6 * NH; k += 4) {
        float p = 0.f;
#pragma unroll
        for (int r = 0; r < 4; ++r) {
            int jj = lane + 64 * r;
            p += ts[jj] * W_g[k * HS + jj];
        }
#pragma unroll
        for (int off = 32; off; off >>= 1) p += __shfl_xor(p, off, 64);
        if (lane == 0) pgs[k] = p + b_g[k];
    }
    __syncthreads();

    if (j < NH) {
        int h = j;
        float gk = expf(pgs[h]) * 0.01f;
        float gl = expf(pgs[NH + h]) * 100.f;
        float qb = fmaxf(pgs[2 * NH + h], 0.f) * 0.1f;
        // softmax over pgs[24..31]
        float m = pgs[3 * NH];
#pragma unroll
        for (int i = 1; i < NH; ++i) m = fmaxf(m, pgs[3 * NH + i]);
        float den = 0.f;
#pragma unroll
        for (int i = 0; i < NH; ++i) den += expf(pgs[3 * NH + i] - m);
        float ga = expf(pgs[3 * NH + h] - m) / den;
        float gi = fminf(fmaxf(pgs[4 * NH + h] * (1.f / 6.f) + 0.5f, 0.f), 1.f) * 0.5f;
        float ge = fmaxf(pgs[5 * NH + h], 0.f);
        int o = s * NH + h;
        prm[0 * NS * NH + o] = gk;
        prm[1 * NS * NH + o] = gl;
        prm[2 * NS * NH + o] = qb;
        prm[3 * NS * NH + o] = ga;
        prm[4 * NS * NH + o] = gi;
        prm[5 * NS * NH + o] = ge;
    }
}

// ---------------- K1: km[t,s,h] + rain/snow split, parallel over (t,s) ----
__global__ __launch_bounds__(256) void k_forcing(
    const float* __restrict__ x, const float* __restrict__ state,
    const float* __restrict__ W_kin, const float* __restrict__ b_kin,
    const float* __restrict__ W_kout, const float* __restrict__ b_kout,
    float* __restrict__ km, float* __restrict__ ps, float* __restrict__ pl)
{
    int wid = (int)((blockIdx.x * (unsigned)blockDim.x + threadIdx.x) >> 6);
    int lane = threadIdx.x & 63;
    if (wid >= NT * NS) return;
    int s = wid & (NS - 1);

    const float* xr = x + (size_t)wid * 6;
    float f0 = xr[2], f1 = xr[3], f2 = xr[4], f3 = xr[5];

    float p[NH];
#pragma unroll
    for (int h = 0; h < NH; ++h) p[h] = 0.f;

#pragma unroll
    for (int r = 0; r < 4; ++r) {
        int j = lane + 64 * r;
        float4 w = reinterpret_cast<const float4*>(W_kin)[j];
        float u = tanhf(b_kin[j] + state[s * HS + j] +
                        f0 * w.x + f1 * w.y + f2 * w.z + f3 * w.w);
#pragma unroll
        for (int h = 0; h < NH; ++h) p[h] += u * W_kout[h * HS + j];
    }
#pragma unroll
    for (int off = 32; off; off >>= 1) {
#pragma unroll
        for (int h = 0; h < NH; ++h) p[h] += __shfl_xor(p[h], off, 64);
    }
    if (lane == 0) {
#pragma unroll
        for (int h = 0; h < NH; ++h)
            km[(size_t)wid * NH + h] = expf(p[h] + b_kout[h]);
    } else if (lane == 1) {
        float prcp = xr[0], t1 = f0, t2 = f1;
        float r = (t1 + t2) / fmaxf(t2 - t1, EPSC);
        r = fminf(fmaxf(r, -1.f), 1.f);
        float vf = acosf(r) * 0.31830988618379067f; // 1/pi
        if (t1 >= 0.f) vf = 0.f;
        if (t2 <= 0.f) vf = 1.f;
        ps[wid] = prcp * vf;
        pl[wid] = prcp * (1.f - vf);
    }
}

// ---------------- K2: the collapsed sequential scan ----------------------
// d (NS,NH,ND) never affects the output: all per-step factors are scalar per
// (s,h) and q only consumes sums. Track only S = sum(d) and snow sf.
#define CHUNK 32
__global__ __launch_bounds__(64) void k_scan(
    const float* __restrict__ x, const float* __restrict__ km,
    const float* __restrict__ ps, const float* __restrict__ pl,
    const float* __restrict__ prm, float* __restrict__ q)
{
    int lane = threadIdx.x;          // 64 lanes = 8 sites x 8 buckets
    int sbase = blockIdx.x * 8;
    int sl = lane >> 3;              // local site 0..7
    int gofs = blockIdx.x * 64 + lane; // global (s*NH + h)

    float gk = prm[0 * NS * NH + gofs];
    float gl = prm[1 * NS * NH + gofs];
    float qb = prm[2 * NS * NH + gofs];
    float ga = prm[3 * NS * NH + gofs];
    float gi = prm[4 * NS * NH + gofs];
    float ge = prm[5 * NS * NH + gofs];

    float S = 0.f, sf = 0.f;

    __shared__ float kml[CHUNK][64];
    __shared__ float auxl[CHUNK][3][8]; // ps, pl, ev per local site

    for (int tb = 0; tb < NT; tb += CHUNK) {
        int cn = min(CHUNK, NT - tb);
        for (int c = 0; c < cn; ++c)
            kml[c][lane] = km[(size_t)(tb + c) * (NS * NH) + gofs];
        for (int idx = lane; idx < cn * 8; idx += 64) {
            int c = idx >> 3, ss = idx & 7;
            int g = (tb + c) * NS + sbase + ss;
            auxl[c][0][ss] = ps[g];
            auxl[c][1][ss] = pl[g];
            auxl[c][2][ss] = x[(size_t)g * 6 + 1]; // evp
        }
        __syncthreads();

        for (int c = 0; c < cn; ++c) {
            float km_v = kml[c][lane];
            float ps_v = auxl[c][0][sl];
            float pl_v = auxl[c][1][sl];
            float ev_v = auxl[c][2][sl];

            float sf1 = sf + ps_v;
            float melt = fminf(sf1, km_v);
            sf = sf1 - melt;
            float w_in = melt + pl_v * gi;
            float e_pot = ev_v * ge;
            S = S + w_in;
            float f_ev = fminf(fmaxf(e_pot / fmaxf(S, EPSC), 0.f), 1.f);
            float S1 = S * (1.f - f_ev);
            float q_s = fmaxf(S1 - gl, 0.f);
            float S2 = S1 - q_s;
            float q_sub = fminf(S2 * gk + qb, S2);
            float f_q = q_sub / fmaxf(S2, EPSC);
            float out = q_s + S2 * f_q;
            S = S2 * (1.f - f_q);

            float v = ga * out;
            v += __shfl_xor(v, 1, 64);
            v += __shfl_xor(v, 2, 64);
            v += __shfl_xor(v, 4, 64);
            if ((lane & 7) == 0) q[(tb + c) * NS + sbase + sl] = v;
        }
        __syncthreads();
    }
}

extern "C" void kernel_launch(void* const* d_in, const int* in_sizes, int n_in,
                              void* d_out, int out_size, void* d_ws, size_t ws_size,
                              hipStream_t stream)
{
    const float* x      = (const float*)d_in[0];
    const float* xc     = (const float*)d_in[1];
    const float* W_fc   = (const float*)d_in[2];
    const float* b_fc   = (const float*)d_in[3];
    const float* W_g    = (const float*)d_in[4];
    const float* b_g    = (const float*)d_in[5];
    const float* W_kin  = (const float*)d_in[6];
    const float* b_kin  = (const float*)d_in[7];
    const float* W_kout = (const float*)d_in[8];
    const float* b_kout = (const float*)d_in[9];
    float* q = (float*)d_out;

    float* ws    = (float*)d_ws;
    float* state = ws + WS_STATE;
    float* prm   = ws + WS_PRM;
    float* km    = ws + WS_KM;
    float* ps    = ws + WS_PS;
    float* pl    = ws + WS_PL;

    hipLaunchKernelGGL(k_params, dim3(NS), dim3(HS), 0, stream,
                       xc, W_fc, b_fc, W_g, b_g, state, prm);

    int nwaves = NT * NS;               // one wave per (t,s)
    int blocks = (nwaves + 3) / 4;      // 4 waves (256 thr) per block
    hipLaunchKernelGGL(k_forcing, dim3(blocks), dim3(256), 0, stream,
                       x, state, W_kin, b_kin, W_kout, b_kout, km, ps, pl);

    hipLaunchKernelGGL(k_scan, dim3(NS / 8), dim3(64), 0, stream,
                       x, km, ps, pl, prm, q);
}

// Round 2
// 51.649 us; speedup vs baseline: 2.9572x; 2.9572x over previous
//
#include <hip/hip_runtime.h>
#include <math.h>

#define NT 365
#define NT2 368
#define NS 128
#define NG 16
#define NH 8
#define HS 256
#define EPSC 1e-6f

// Workspace layout (floats):
//   state: NS*HS   @ 0        (32768)
//   prm:   6*NS*NH @ 32768    (6144)   order: gk, gl, qb, ga, gi, ge
//   kmb:   16*NT2*64  @ 38912    (376832)  block-major km
//   aux4b: 16*NT2*8*4 @ 415744   (188416)  block-major {ps,pl,ev,0}
// total 604160 floats = 2,416,640 bytes
#define WS_STATE 0
#define WS_PRM   32768
#define WS_KM    38912
#define WS_AUX   415744

__device__ __forceinline__ float fast_rcp(float v) {
#if __has_builtin(__builtin_amdgcn_rcpf)
    return __builtin_amdgcn_rcpf(v);
#else
    return 1.f / v;
#endif
}
__device__ __forceinline__ float fast_tanh(float xv) {
    float e = __expf(2.f * xv);           // large-x overflow -> inf -> rcp -> 0 -> 1  (correct limit)
    return 1.f - 2.f * fast_rcp(e + 1.f);
}

// ---------------- K0: per-site state + parameter heads -----------------
__global__ __launch_bounds__(256) void k_params(
    const float* __restrict__ xc, const float* __restrict__ W_fc,
    const float* __restrict__ b_fc, const float* __restrict__ W_g,
    const float* __restrict__ b_g, float* __restrict__ state,
    float* __restrict__ prm)
{
    int s = blockIdx.x;
    int j = threadIdx.x;
    __shared__ float ts[HS];
    __shared__ float pgs[6 * NH];

    float acc = b_fc[j];
    const float* xrow = xc + s * NG;
#pragma unroll
    for (int g = 0; g < NG; ++g) acc += xrow[g] * W_fc[j * NG + g];
    state[s * HS + j] = acc;
    ts[j] = tanhf(acc);
    __syncthreads();

    int wave = j >> 6, lane = j & 63;
    for (int k = wave; k < 6 * NH; k += 4) {
        float p = 0.f;
#pragma unroll
        for (int r = 0; r < 4; ++r) {
            int jj = lane + 64 * r;
            p += ts[jj] * W_g[k * HS + jj];
        }
#pragma unroll
        for (int off = 32; off; off >>= 1) p += __shfl_xor(p, off, 64);
        if (lane == 0) pgs[k] = p + b_g[k];
    }
    __syncthreads();

    if (j < NH) {
        int h = j;
        float gk = expf(pgs[h]) * 0.01f;
        float gl = expf(pgs[NH + h]) * 100.f;
        float qb = fmaxf(pgs[2 * NH + h], 0.f) * 0.1f;
        float m = pgs[3 * NH];
#pragma unroll
        for (int i = 1; i < NH; ++i) m = fmaxf(m, pgs[3 * NH + i]);
        float den = 0.f;
#pragma unroll
        for (int i = 0; i < NH; ++i) den += expf(pgs[3 * NH + i] - m);
        float ga = expf(pgs[3 * NH + h] - m) / den;
        float gi = fminf(fmaxf(pgs[4 * NH + h] * (1.f / 6.f) + 0.5f, 0.f), 1.f) * 0.5f;
        float ge = fmaxf(pgs[5 * NH + h], 0.f);
        int o = s * NH + h;
        prm[0 * NS * NH + o] = gk;
        prm[1 * NS * NH + o] = gl;
        prm[2 * NS * NH + o] = qb;
        prm[3 * NS * NH + o] = ga;
        prm[4 * NS * NH + o] = gi;
        prm[5 * NS * NH + o] = ge;
    }
}

// ---------------- K1: km + {ps,pl,ev} in block-major layout -------------
// 5888 wave-slots x 8 (t,s) pairs each. Two-phase head: u[j] -> LDS
// (pad-36 transposed layout), then lane (h,jg) dots contiguous float4 runs
// against LDS-staged transposed W_kout; 3 shfl_xor finish the reduce.
__global__ __launch_bounds__(256) void k_forcing(
    const float* __restrict__ x, const float* __restrict__ state,
    const float* __restrict__ W_kin, const float* __restrict__ b_kin,
    const float* __restrict__ W_kout, const float* __restrict__ b_kout,
    float* __restrict__ kmb, float* __restrict__ aux4b)
{
    __shared__ __align__(16) float lds_wkt[8 * 292];
    __shared__ __align__(16) float lds_u[4 * 288];

    for (int idx = threadIdx.x; idx < NH * HS; idx += 256) {
        int hh = idx >> 8, j = idx & 255;
        lds_wkt[hh * 292 + (j & 7) * 36 + (j >> 3)] = W_kout[idx];
    }
    __syncthreads();

    int wave = threadIdx.x >> 6;
    int lane = threadIdx.x & 63;
    int wbase = blockIdx.x * 4 + wave;      // 0..5887
    float* uw = lds_u + wave * 288;
    int h = lane >> 3, jg = lane & 7;
    float4* aux4v = (float4*)aux4b;

    for (int g = 0; g < 8; ++g) {
        int wid = wbase + g * 5888;         // 0..47103
        int t = wid >> 7, s = wid & 127;
        int kout = ((s >> 3) * NT2 + t) * 64 + (s & 7) * 8;
        int aout = ((s >> 3) * NT2 + t) * 8 + (s & 7);
        if (t >= NT) {                      // zero-pad tail (wave-uniform branch)
            if (lane < 8) kmb[kout + lane] = 0.f;
            if (lane == 8) aux4v[aout] = make_float4(0.f, 0.f, 0.f, 0.f);
            continue;
        }
        const float* xr = x + wid * 6;
        float f0 = xr[2], f1 = xr[3], f2 = xr[4], f3 = xr[5];
#pragma unroll
        for (int r = 0; r < 4; ++r) {
            int j = lane + 64 * r;
            float4 w = ((const float4*)W_kin)[j];
            float uval = fast_tanh(b_kin[j] + state[s * HS + j] +
                                   f0 * w.x + f1 * w.y + f2 * w.z + f3 * w.w);
            uw[jg * 36 + (lane >> 3) + 8 * r] = uval;   // u[j] at (j&7)*36+(j>>3)
        }
        if (lane == 0) {
            float prcp = xr[0], ev = xr[1];
            float r_ = (f0 + f1) / fmaxf(f1 - f0, EPSC);
            r_ = fminf(fmaxf(r_, -1.f), 1.f);
            float vf = acosf(r_) * 0.31830988618379067f;   // 1/pi
            if (f0 >= 0.f) vf = 0.f;
            if (f1 <= 0.f) vf = 1.f;
            aux4v[aout] = make_float4(prcp * vf, prcp * (1.f - vf), ev, 0.f);
        }
        float acc = 0.f;
        const float4* uu = (const float4*)(uw + jg * 36);
        const float4* ww = (const float4*)(lds_wkt + h * 292 + jg * 36);
#pragma unroll
        for (int k = 0; k < 8; ++k) {
            float4 a = uu[k], b = ww[k];
            acc += a.x * b.x; acc += a.y * b.y; acc += a.z * b.z; acc += a.w * b.w;
        }
        acc += __shfl_xor(acc, 1, 64);
        acc += __shfl_xor(acc, 2, 64);
        acc += __shfl_xor(acc, 4, 64);
        if (jg == 0) kmb[kout + h] = __expf(acc + b_kout[h]);
    }
}

// ---------------- K2: collapsed scan, division/shuffle-free inner step ---
// Register-staged double-buffered chunks of 16 steps; per-step LDS write of
// ga*out; per-chunk transposed-LDS reduce over h -> q.
__global__ __launch_bounds__(64, 1) void k_scan(
    const float* __restrict__ kmb, const float* __restrict__ aux4b,
    const float* __restrict__ prm, float* __restrict__ q)
{
    int lane = threadIdx.x;
    int blk = blockIdx.x;               // 0..15
    int sl = lane >> 3;                 // local site
    int sbase = blk * 8;
    int gofs = blk * 64 + lane;         // s*NH + h

    float gk = prm[0 * NS * NH + gofs];
    float gl = prm[1 * NS * NH + gofs];
    float qb = prm[2 * NS * NH + gofs];
    float ga = prm[3 * NS * NH + gofs];
    float gi = prm[4 * NS * NH + gofs];
    float ge = prm[5 * NS * NH + gofs];

    __shared__ float out_lds[64 * 17];

    float S = 0.f, sf = 0.f;
    float kmA[16], kmB[16];
    float4 axA[16], axB[16];

    const float*  kmBlk = kmb + blk * (NT2 * 64);
    const float4* axBlk = (const float4*)aux4b + blk * (NT2 * 8);

#define LOADC(tb, KM, AX) _Pragma("unroll") \
    for (int c = 0; c < 16; ++c) { \
        KM[c] = kmBlk[(tb + c) * 64 + lane]; \
        AX[c] = axBlk[(tb + c) * 8 + sl]; \
    }

#define STEPC(KM, AX) _Pragma("unroll") \
    for (int c = 0; c < 16; ++c) { \
        float km_v = KM[c]; float4 a = AX[c]; \
        float sf1 = sf + a.x; \
        float melt = fminf(sf1, km_v); \
        sf = sf1 - melt; \
        S = S + melt + a.y * gi; \
        float S1 = fmaxf(S - a.z * ge, 0.f); \
        float q_s = fmaxf(S1 - gl, 0.f); \
        float S2 = fminf(S1, gl); \
        float q_sub = fminf(S2 * gk + qb, S2); \
        S = S2 - q_sub; \
        out_lds[lane * 17 + c] = ga * (q_s + q_sub); \
    }

#define REDC(tb) _Pragma("unroll") \
    for (int it = 0; it < 2; ++it) { \
        int idx = it * 64 + lane; int c = idx >> 3; int ss = idx & 7; \
        float sum = 0.f; \
        _Pragma("unroll") \
        for (int hh = 0; hh < 8; ++hh) sum += out_lds[(ss * 8 + hh) * 17 + c]; \
        int t = tb + c; \
        if (t < NT) q[t * NS + sbase + ss] = sum; \
    }

    LOADC(0, kmA, axA);
    for (int cb = 0; cb < 22; cb += 2) {
        LOADC((cb + 1) * 16, kmB, axB);
        STEPC(kmA, axA);
        LOADC((cb + 2) * 16, kmA, axA);
        REDC(cb * 16);
        STEPC(kmB, axB);
        REDC((cb + 1) * 16);
    }
    STEPC(kmA, axA);
    REDC(22 * 16);
#undef LOADC
#undef STEPC
#undef REDC
}

extern "C" void kernel_launch(void* const* d_in, const int* in_sizes, int n_in,
                              void* d_out, int out_size, void* d_ws, size_t ws_size,
                              hipStream_t stream)
{
    const float* x      = (const float*)d_in[0];
    const float* xc     = (const float*)d_in[1];
    const float* W_fc   = (const float*)d_in[2];
    const float* b_fc   = (const float*)d_in[3];
    const float* W_g    = (const float*)d_in[4];
    const float* b_g    = (const float*)d_in[5];
    const float* W_kin  = (const float*)d_in[6];
    const float* b_kin  = (const float*)d_in[7];
    const float* W_kout = (const float*)d_in[8];
    const float* b_kout = (const float*)d_in[9];
    float* q = (float*)d_out;

    float* ws    = (float*)d_ws;
    float* state = ws + WS_STATE;
    float* prm   = ws + WS_PRM;
    float* kmb   = ws + WS_KM;
    float* aux4b = ws + WS_AUX;

    hipLaunchKernelGGL(k_params, dim3(NS), dim3(HS), 0, stream,
                       xc, W_fc, b_fc, W_g, b_g, state, prm);

    hipLaunchKernelGGL(k_forcing, dim3(1472), dim3(256), 0, stream,
                       x, state, W_kin, b_kin, W_kout, b_kout, kmb, aux4b);

    hipLaunchKernelGGL(k_scan, dim3(16), dim3(64), 0, stream,
                       kmb, aux4b, prm, q);
}

// Round 3
// 47.725 us; speedup vs baseline: 3.2004x; 1.0822x over previous
//
#include <hip/hip_runtime.h>
#include <math.h>

#define NT 365
#define NT2 368
#define NS 128
#define NG 16
#define NH 8
#define HS 256
#define EPSC 1e-6f

// Workspace layout (floats):
//   prm: 6*NS*NH @ 0     (6144)   order: gk, gl, qb, ga, gi, ge
//   P:   16*NT2*64*4 @ 8192      packed float4 {km, ps, pl, ev} per (blk,t,lane)
#define WS_PRM 0
#define WS_P   8192

__device__ __forceinline__ float fast_rcp(float v) {
#if __has_builtin(__builtin_amdgcn_rcpf)
    return __builtin_amdgcn_rcpf(v);
#else
    return 1.f / v;
#endif
}
__device__ __forceinline__ float fast_tanh(float xv) {
    float e = __expf(2.f * xv);   // overflow -> inf -> rcp -> 0 -> tanh=1 (correct limit)
    return 1.f - 2.f * fast_rcp(e + 1.f);
}

// ---------------- K_main: forcing (+ fused per-site param heads) ----------
// 1472 blocks x 256. Each wave owns one site s (constant across its 8 time
// slots) and computes km[t,s,:] + {ps,pl,ev}, writing packed float4 in the
// scan's lane-major layout. Blocks 0..127 additionally compute prm[site].
__global__ __launch_bounds__(256) void k_main(
    const float* __restrict__ x, const float* __restrict__ xc,
    const float* __restrict__ W_fc, const float* __restrict__ b_fc,
    const float* __restrict__ W_g, const float* __restrict__ b_g,
    const float* __restrict__ W_kin, const float* __restrict__ b_kin,
    const float* __restrict__ W_kout, const float* __restrict__ b_kout,
    float* __restrict__ prm, float4* __restrict__ P)
{
    __shared__ __align__(16) float lds_wkt[8 * 292];
    __shared__ __align__(16) float lds_u[4 * 288];
    __shared__ float ts[HS];
    __shared__ float pgs[6 * NH];

    int tid = threadIdx.x;
    int wave = tid >> 6, lane = tid & 63;
    int wbase = blockIdx.x * 4 + wave;      // 0..5887
    int s = wbase & 127;                    // constant per wave
    int t0 = wbase >> 7;                    // 0..45
    int blk = s >> 3;
    int h = lane >> 3, jg = lane & 7;

    // stage transposed W_kout: value for (h', j) at h'*292 + (j&7)*36 + (j>>3)
    for (int idx = tid; idx < NH * HS; idx += 256) {
        int hh = idx >> 8, j = idx & 255;
        lds_wkt[hh * 292 + (j & 7) * 36 + (j >> 3)] = W_kout[idx];
    }

    // fused params phase A (blocks 0..127): ts[j] = tanh(state[s0, j])
    int s0 = blockIdx.x;
    float acc0 = 0.f;
    if (s0 < NS) {
        acc0 = b_fc[tid];
        const float* xrow = xc + s0 * NG;
#pragma unroll
        for (int g = 0; g < NG; ++g) acc0 += xrow[g] * W_fc[tid * NG + g];
        ts[tid] = tanhf(acc0);
    }
    __syncthreads();

    // per-wave setup: W_kin row, ustate = b_kin + b_fc + xc@W_fc.T, W_kout regs
    float4 w4[4];
    float ustate[4];
    float xcv[16];
#pragma unroll
    for (int i = 0; i < 4; ++i)
        ((float4*)xcv)[i] = ((const float4*)(xc + s * NG))[i];
#pragma unroll
    for (int r = 0; r < 4; ++r) {
        int j = lane + 64 * r;
        w4[r] = ((const float4*)W_kin)[j];
        float a = b_fc[j] + b_kin[j];
        const float4* wf = (const float4*)(W_fc + j * NG);
#pragma unroll
        for (int i = 0; i < 4; ++i) {
            float4 wv = wf[i];
            a += xcv[4 * i] * wv.x + xcv[4 * i + 1] * wv.y +
                 xcv[4 * i + 2] * wv.z + xcv[4 * i + 3] * wv.w;
        }
        ustate[r] = a;
    }
    float4 wwr[8];
    {
        const float4* wwp = (const float4*)(lds_wkt + h * 292 + jg * 36);
#pragma unroll
        for (int k = 0; k < 8; ++k) wwr[k] = wwp[k];
    }
    float bko = b_kout[h];

    // fused params phase B (blocks 0..127): pg heads -> prm
    if (s0 < NS) {
        for (int k = wave; k < 6 * NH; k += 4) {
            float p = 0.f;
#pragma unroll
            for (int r = 0; r < 4; ++r) {
                int jj = lane + 64 * r;
                p += ts[jj] * W_g[k * HS + jj];
            }
#pragma unroll
            for (int off = 32; off; off >>= 1) p += __shfl_xor(p, off, 64);
            if (lane == 0) pgs[k] = p + b_g[k];
        }
        __syncthreads();
        if (tid < NH) {
            int hh = tid;
            float gk = expf(pgs[hh]) * 0.01f;
            float gl = expf(pgs[NH + hh]) * 100.f;
            float qb = fmaxf(pgs[2 * NH + hh], 0.f) * 0.1f;
            float m = pgs[3 * NH];
#pragma unroll
            for (int i = 1; i < NH; ++i) m = fmaxf(m, pgs[3 * NH + i]);
            float den = 0.f;
#pragma unroll
            for (int i = 0; i < NH; ++i) den += expf(pgs[3 * NH + i] - m);
            float ga = expf(pgs[3 * NH + hh] - m) / den;
            float gi = fminf(fmaxf(pgs[4 * NH + hh] * (1.f / 6.f) + 0.5f, 0.f), 1.f) * 0.5f;
            float ge = fmaxf(pgs[5 * NH + hh], 0.f);
            int o = s0 * NH + hh;
            prm[0 * NS * NH + o] = gk;
            prm[1 * NS * NH + o] = gl;
            prm[2 * NS * NH + o] = qb;
            prm[3 * NS * NH + o] = ga;
            prm[4 * NS * NH + o] = gi;
            prm[5 * NS * NH + o] = ge;
        }
    }

    // main forcing loop: 8 time slots per wave
    float* uw = lds_u + wave * 288;
    for (int g = 0; g < 8; ++g) {
        int t = t0 + g * 46;                     // < 368
        int pidx = (blk * NT2 + t) * 64 + (s & 7) * 8;
        if (t >= NT) {                           // wave-uniform zero-pad
            if (jg == 0) P[pidx + h] = make_float4(0.f, 0.f, 0.f, 0.f);
            continue;
        }
        const float* xr = x + (size_t)(t * NS + s) * 6;
        float prcp = xr[0], ev = xr[1], f0 = xr[2], f1 = xr[3], f2 = xr[4], f3 = xr[5];
#pragma unroll
        for (int r = 0; r < 4; ++r) {
            float uval = fast_tanh(ustate[r] + f0 * w4[r].x + f1 * w4[r].y +
                                   f2 * w4[r].z + f3 * w4[r].w);
            uw[jg * 36 + (lane >> 3) + 8 * r] = uval;
        }
        // rain/snow split (uniform; all lanes)
        float r_ = (f0 + f1) / fmaxf(f1 - f0, EPSC);
        r_ = fminf(fmaxf(r_, -1.f), 1.f);
        float vf = acosf(r_) * 0.31830988618379067f;   // 1/pi
        if (f0 >= 0.f) vf = 0.f;
        if (f1 <= 0.f) vf = 1.f;
        float psv = prcp * vf;
        float plv = prcp * (1.f - vf);
        // dot u . W_kout[h]
        float acc = 0.f;
        const float4* uu = (const float4*)(uw + jg * 36);
#pragma unroll
        for (int k = 0; k < 8; ++k) {
            float4 a = uu[k], b = wwr[k];
            acc += a.x * b.x; acc += a.y * b.y; acc += a.z * b.z; acc += a.w * b.w;
        }
        acc += __shfl_xor(acc, 1, 64);
        acc += __shfl_xor(acc, 2, 64);
        acc += __shfl_xor(acc, 4, 64);
        if (jg == 0) {
            float kmv = __expf(acc + bko);
            P[pidx + h] = make_float4(kmv, psv, plv, ev);
        }
    }
}

// ---------------- K_scan: collapsed scan over packed float4 stream --------
__global__ __launch_bounds__(64, 1) void k_scan(
    const float4* __restrict__ P, const float* __restrict__ prm,
    float* __restrict__ q)
{
    int lane = threadIdx.x;
    int blk = blockIdx.x;               // 0..15
    int sbase = blk * 8;
    int gofs = blk * 64 + lane;         // s*NH + h

    float gk = prm[0 * NS * NH + gofs];
    float gl = prm[1 * NS * NH + gofs];
    float qb = prm[2 * NS * NH + gofs];
    float ga = prm[3 * NS * NH + gofs];
    float gi = prm[4 * NS * NH + gofs];
    float ge = prm[5 * NS * NH + gofs];

    __shared__ float out_lds[64 * 17];

    float S = 0.f, sf = 0.f;
    float4 A[16], B[16];
    const float4* Pb = P + blk * (NT2 * 64);

#define LOADC(tb, BUF) _Pragma("unroll") \
    for (int c = 0; c < 16; ++c) BUF[c] = Pb[(tb + c) * 64 + lane];

#define STEPC(BUF) _Pragma("unroll") \
    for (int c = 0; c < 16; ++c) { \
        float4 a = BUF[c]; \
        float sf1 = sf + a.y; \
        float melt = fminf(sf1, a.x); \
        sf = sf1 - melt; \
        S = S + (melt + a.z * gi); \
        float S1 = fmaxf(S - a.w * ge, 0.f); \
        float q_s = fmaxf(S1 - gl, 0.f); \
        float S2 = fminf(S1, gl); \
        float q_sub = fminf(S2 * gk + qb, S2); \
        S = S2 - q_sub; \
        out_lds[lane * 17 + c] = ga * (q_s + q_sub); \
    }

#define REDC(tb) _Pragma("unroll") \
    for (int it = 0; it < 2; ++it) { \
        int idx = it * 64 + lane; int c = idx >> 3; int ss = idx & 7; \
        float sum = 0.f; \
        _Pragma("unroll") \
        for (int hh = 0; hh < 8; ++hh) sum += out_lds[(ss * 8 + hh) * 17 + c]; \
        int t = tb + c; \
        if (t < NT) q[t * NS + sbase + ss] = sum; \
    }

    LOADC(0, A);
    for (int cb = 0; cb < 22; cb += 2) {
        LOADC((cb + 1) * 16, B);
        STEPC(A);
        LOADC((cb + 2) * 16, A);
        REDC(cb * 16);
        STEPC(B);
        REDC((cb + 1) * 16);
    }
    STEPC(A);
    REDC(22 * 16);
#undef LOADC
#undef STEPC
#undef REDC
}

extern "C" void kernel_launch(void* const* d_in, const int* in_sizes, int n_in,
                              void* d_out, int out_size, void* d_ws, size_t ws_size,
                              hipStream_t stream)
{
    const float* x      = (const float*)d_in[0];
    const float* xc     = (const float*)d_in[1];
    const float* W_fc   = (const float*)d_in[2];
    const float* b_fc   = (const float*)d_in[3];
    const float* W_g    = (const float*)d_in[4];
    const float* b_g    = (const float*)d_in[5];
    const float* W_kin  = (const float*)d_in[6];
    const float* b_kin  = (const float*)d_in[7];
    const float* W_kout = (const float*)d_in[8];
    const float* b_kout = (const float*)d_in[9];
    float* q = (float*)d_out;

    float* ws  = (float*)d_ws;
    float* prm = ws + WS_PRM;
    float4* P  = (float4*)(ws + WS_P);

    hipLaunchKernelGGL(k_main, dim3(1472), dim3(256), 0, stream,
                       x, xc, W_fc, b_fc, W_g, b_g, W_kin, b_kin,
                       W_kout, b_kout, prm, P);

    hipLaunchKernelGGL(k_scan, dim3(16), dim3(64), 0, stream,
                       P, prm, q);
}

// Round 4
// 38.128 us; speedup vs baseline: 4.0059x; 1.2517x over previous
//
#include <hip/hip_runtime.h>
#include <math.h>

#define NT 365
#define NT2 368
#define NS 128
#define NG 16
#define NH 8
#define HS 256
#define NSNH (NS * NH)
#define EPSC 1e-6f

// Workspace layout (floats):
//   prm: 6*NS*NH @ 0      order: gk, gl, qb, ga, gi, ge
//   P:   16*NT2*64*4 @ 8192   packed float4 {km, ps, pl, ev} per (blk,t,lane)
#define WS_PRM 0
#define WS_P   8192

__device__ __forceinline__ float fast_rcp(float v) {
#if __has_builtin(__builtin_amdgcn_rcpf)
    return __builtin_amdgcn_rcpf(v);
#else
    return 1.f / v;
#endif
}
__device__ __forceinline__ float fast_tanh(float xv) {
    float e = __expf(2.f * xv);   // overflow -> inf -> rcp -> 0 -> tanh=1 (correct limit)
    return 1.f - 2.f * fast_rcp(e + 1.f);
}

// ---------------- K_main: forcing (+ fused per-site param heads) ----------
// 1536 blocks x 256. Each BLOCK owns one site s = blockIdx&127 (ustate
// computed once per block into LDS; W_kin/W_kout staged in LDS). Wave w
// handles t0 = (blockIdx>>7)*4 + w, time slots t = t0 + 48g, g=0..7.
// Blocks 0..127 additionally compute prm[site].
__global__ __launch_bounds__(256) void k_main(
    const float* __restrict__ x, const float* __restrict__ xc,
    const float* __restrict__ W_fc, const float* __restrict__ b_fc,
    const float* __restrict__ W_g, const float* __restrict__ b_g,
    const float* __restrict__ W_kin, const float* __restrict__ b_kin,
    const float* __restrict__ W_kout, const float* __restrict__ b_kout,
    float* __restrict__ prm, float4* __restrict__ P)
{
    __shared__ float us[HS];                     // ustate = state + b_kin
    __shared__ float ts[HS];                     // tanh(state), param blocks
    __shared__ __align__(16) float4 wkin_lds[HS];
    __shared__ float wko_lds[8 * 260];           // padded rows (banks 4h+4k)
    __shared__ __align__(16) float lds_u[4 * 288];
    __shared__ float pgs[6 * NH];

    int tid = threadIdx.x;
    int wave = tid >> 6, lane = tid & 63;
    int s = blockIdx.x & 127;
    int t0 = (blockIdx.x >> 7) * 4 + wave;       // 0..47
    int h = lane >> 3, jg = lane & 7;

    // stage W_kin (4KB) and W_kout (padded 8.3KB)
    wkin_lds[tid] = ((const float4*)W_kin)[tid];
#pragma unroll
    for (int i = 0; i < 8; ++i) {
        int idx = tid + 256 * i;
        wko_lds[(idx >> 8) * 260 + (idx & 255)] = W_kout[idx];
    }
    // state row tid for this block's site (one W_fc pass per block)
    {
        float a = b_fc[tid];
        const float4* wf = (const float4*)(W_fc + tid * NG);
        const float* xr = xc + s * NG;
#pragma unroll
        for (int i = 0; i < 4; ++i) {
            float4 w = wf[i];
            a += xr[4*i] * w.x + xr[4*i+1] * w.y + xr[4*i+2] * w.z + xr[4*i+3] * w.w;
        }
        ts[tid] = tanhf(a);
        us[tid] = a + b_kin[tid];
    }
    __syncthreads();

    // per-wave registers from LDS (read once, reused over 8 slots)
    float ust[4]; float4 w4[4];
#pragma unroll
    for (int r = 0; r < 4; ++r) {
        ust[r] = us[lane + 64 * r];
        w4[r]  = wkin_lds[lane + 64 * r];
    }
    float4 wwr[8];
#pragma unroll
    for (int k = 0; k < 8; ++k)
        wwr[k] = *(const float4*)(wko_lds + h * 260 + jg * 32 + 4 * k);
    float bko = b_kout[h];

    // fused param heads for blocks 0..127 (site == blockIdx)
    if (blockIdx.x < NS) {
        for (int k = wave; k < 6 * NH; k += 4) {
            float p = 0.f;
#pragma unroll
            for (int r = 0; r < 4; ++r) {
                int jj = lane + 64 * r;
                p += ts[jj] * W_g[k * HS + jj];
            }
#pragma unroll
            for (int off = 32; off; off >>= 1) p += __shfl_xor(p, off, 64);
            if (lane == 0) pgs[k] = p + b_g[k];
        }
        __syncthreads();
        if (tid < NH) {
            int hh = tid;
            float gk = expf(pgs[hh]) * 0.01f;
            float gl = expf(pgs[NH + hh]) * 100.f;
            float qb = fmaxf(pgs[2 * NH + hh], 0.f) * 0.1f;
            float m = pgs[3 * NH];
#pragma unroll
            for (int i = 1; i < NH; ++i) m = fmaxf(m, pgs[3 * NH + i]);
            float den = 0.f;
#pragma unroll
            for (int i = 0; i < NH; ++i) den += expf(pgs[3 * NH + i] - m);
            float ga = expf(pgs[3 * NH + hh] - m) / den;
            float gi = fminf(fmaxf(pgs[4 * NH + hh] * (1.f / 6.f) + 0.5f, 0.f), 1.f) * 0.5f;
            float ge = fmaxf(pgs[5 * NH + hh], 0.f);
            int o = s * NH + hh;
            prm[0 * NSNH + o] = gk;
            prm[1 * NSNH + o] = gl;
            prm[2 * NSNH + o] = qb;
            prm[3 * NSNH + o] = ga;
            prm[4 * NSNH + o] = gi;
            prm[5 * NSNH + o] = ge;
        }
    }

    // main forcing loop: 8 time slots per wave
    float* uw = lds_u + wave * 288;
    int ubase = lane + 4 * (lane >> 5);          // u[j] at j + 4*(j>>5)
    const float4* uuP = (const float4*)(uw + jg * 36);
    int sblk = s >> 3, srem = (s & 7) * 8;

#pragma unroll
    for (int g = 0; g < 8; ++g) {
        int t = t0 + 48 * g;                     // 0..383
        if (t >= NT) {                           // wave-uniform tail
            if (t < NT2 && jg == 0)
                P[(sblk * NT2 + t) * 64 + srem + h] = make_float4(0.f, 0.f, 0.f, 0.f);
            continue;
        }
        const float2* xr2 = (const float2*)(x + (size_t)(t * NS + s) * 6);
        float2 a01 = xr2[0], a23 = xr2[1], a45 = xr2[2];
        float prcp = a01.x, ev = a01.y;
        float f0 = a23.x, f1 = a23.y, f2 = a45.x, f3 = a45.y;
#pragma unroll
        for (int r = 0; r < 4; ++r) {
            float uval = fast_tanh(ust[r] + f0 * w4[r].x + f1 * w4[r].y +
                                   f2 * w4[r].z + f3 * w4[r].w);
            uw[ubase + 72 * r] = uval;
        }
        float r_ = (f0 + f1) / fmaxf(f1 - f0, EPSC);
        r_ = fminf(fmaxf(r_, -1.f), 1.f);
        float vf = acosf(r_) * 0.31830988618379067f;   // 1/pi
        if (f0 >= 0.f) vf = 0.f;
        if (f1 <= 0.f) vf = 1.f;
        float psv = prcp * vf;
        float plv = prcp * (1.f - vf);
        float acc = 0.f;
#pragma unroll
        for (int k = 0; k < 8; ++k) {
            float4 a = uuP[k], b = wwr[k];
            acc += a.x * b.x + a.y * b.y + a.z * b.z + a.w * b.w;
        }
        acc += __shfl_xor(acc, 1, 64);
        acc += __shfl_xor(acc, 2, 64);
        acc += __shfl_xor(acc, 4, 64);
        if (jg == 0)
            P[(sblk * NT2 + t) * 64 + srem + h] =
                make_float4(__expf(acc + bko), psv, plv, ev);
    }
}

// ---------------- K_scan: collapsed scan, 12-slot step, 3-deep pipeline ---
__global__ __launch_bounds__(64, 1) void k_scan(
    const float4* __restrict__ P, const float* __restrict__ prm,
    float* __restrict__ q)
{
    int lane = threadIdx.x;
    int blk = blockIdx.x;               // 0..15
    int sbase = blk * 8;
    int gofs = blk * 64 + lane;         // s*NH + h

    float gk = prm[0 * NSNH + gofs];
    float gl = prm[1 * NSNH + gofs];
    float qb = prm[2 * NSNH + gofs];
    float gi = prm[4 * NSNH + gofs];
    float ge = prm[5 * NSNH + gofs];
    float c1 = 1.f - gk, nqb = -qb, nge = -ge;
    int ss0 = lane & 7;
    float gar[8];                        // ga[site ss0][h] for the REDC role
#pragma unroll
    for (int hh = 0; hh < 8; ++hh)
        gar[hh] = prm[3 * NSNH + (sbase + ss0) * 8 + hh];

    __shared__ float out_lds[64 * 17];
    float S = 0.f, sf = 0.f;
    const float4* Pb = P + (size_t)blk * (NT2 * 64) + lane;

    float4 A[16], B[16], C[16];

#define LOADC(ci, BUF) { const float4* p_ = Pb + (ci) * 1024; _Pragma("unroll") \
    for (int c = 0; c < 16; ++c) BUF[c] = p_[c * 64]; }

#define WORKC(BUF, tb) { \
    _Pragma("unroll") for (int c = 0; c < 16; ++c) { \
        float4 a = BUF[c]; \
        float sf1 = sf + a.y; \
        float melt = fminf(sf1, a.x); \
        sf = sf1 - melt; \
        float Sw = S + fmaf(a.z, gi, melt); \
        float t2v = fmaf(a.w, nge, Sw); \
        float S1 = fmaxf(t2v, 0.f); \
        float S2 = __builtin_amdgcn_fmed3f(t2v, 0.f, gl); \
        float Sn = fmaxf(fmaf(S2, c1, nqb), 0.f); \
        S = Sn; \
        out_lds[lane * 17 + c] = S1 - Sn; \
    } \
    _Pragma("unroll") for (int it = 0; it < 2; ++it) { \
        int idx = it * 64 + lane; int c = idx >> 3; \
        float sum = 0.f; \
        _Pragma("unroll") for (int hh = 0; hh < 8; ++hh) \
            sum = fmaf(gar[hh], out_lds[(ss0 * 8 + hh) * 17 + c], sum); \
        int t = (tb) + c; \
        if (t < NT) q[t * NS + sbase + ss0] = sum; \
    } }

    LOADC(0, A); LOADC(1, B);
    for (int k = 0; k < 7; ++k) {
        int c3 = 3 * k;
        LOADC(c3 + 2, C); WORKC(A, c3 * 16);
        LOADC(c3 + 3, A); WORKC(B, (c3 + 1) * 16);
        LOADC(c3 + 4, B); WORKC(C, (c3 + 2) * 16);
    }
    WORKC(A, 21 * 16); WORKC(B, 22 * 16);
#undef LOADC
#undef WORKC
}

extern "C" void kernel_launch(void* const* d_in, const int* in_sizes, int n_in,
                              void* d_out, int out_size, void* d_ws, size_t ws_size,
                              hipStream_t stream)
{
    const float* x      = (const float*)d_in[0];
    const float* xc     = (const float*)d_in[1];
    const float* W_fc   = (const float*)d_in[2];
    const float* b_fc   = (const float*)d_in[3];
    const float* W_g    = (const float*)d_in[4];
    const float* b_g    = (const float*)d_in[5];
    const float* W_kin  = (const float*)d_in[6];
    const float* b_kin  = (const float*)d_in[7];
    const float* W_kout = (const float*)d_in[8];
    const float* b_kout = (const float*)d_in[9];
    float* q = (float*)d_out;

    float* ws  = (float*)d_ws;
    float* prm = ws + WS_PRM;
    float4* P  = (float4*)(ws + WS_P);

    hipLaunchKernelGGL(k_main, dim3(1536), dim3(256), 0, stream,
                       x, xc, W_fc, b_fc, W_g, b_g, W_kin, b_kin,
                       W_kout, b_kout, prm, P);

    hipLaunchKernelGGL(k_scan, dim3(16), dim3(64), 0, stream,
                       P, prm, q);
}